// Round 1
// baseline (6412.608 us; speedup 1.0000x reference)
//
#include <hip/hip_runtime.h>
#include <math.h>

#define B_ 64
#define T_ 2048
#define E_ 128
#define H_ 128
#define G3_ 384   // 3*H
#define C_ 32
#define M_ (T_ * B_)   // 131072 tokens

// ---------------------------------------------------------------------------
// K1/K3: gi[m][g] = bias[g] + dot(w[g][:], row_m[:]) ; m = t*B + b
// GATHER: row_m = emb[x[b*T+t]] ; else row_m = src[m]
// Weight-stationary: thread g holds w[g][0:128] in 128 VGPRs.
// ---------------------------------------------------------------------------
template <bool GATHER>
__global__ __launch_bounds__(384, 2) void gates_gemm(
    const float* __restrict__ src,   // emb [V,128] or y [M,128]
    const int*   __restrict__ xidx,  // x [B,T] or nullptr
    const float* __restrict__ w,     // [384,128]
    const float* __restrict__ bias,  // [384]
    float* __restrict__ gi)          // [M,384]
{
    const int g = threadIdx.x;  // 0..383
    float4 wr[32];
    const float4* w4 = (const float4*)(w + g * 128);
#pragma unroll
    for (int i = 0; i < 32; i++) wr[i] = w4[i];
    const float bg = bias[g];

    __shared__ __align__(16) float rows[8][128];

    for (int grp = blockIdx.x; grp < M_ / 8; grp += gridDim.x) {
        const int m0 = grp * 8;
        __syncthreads();  // protect rows[] from readers of previous iter
        for (int i = g; i < 8 * 128; i += 384) {
            const int mm = m0 + (i >> 7);
            const int k = i & 127;
            long row;
            if (GATHER) {
                const int t = mm >> 6;      // m = t*B + b, B=64
                const int b = mm & 63;
                row = (long)xidx[b * T_ + t];
            } else {
                row = mm;
            }
            rows[i >> 7][k] = src[row * 128 + k];
        }
        __syncthreads();
#pragma unroll
        for (int s = 0; s < 8; s++) {
            const float4* h4 = (const float4*)rows[s];
            float a0 = bg, a1 = 0.f, a2 = 0.f, a3 = 0.f;
#pragma unroll
            for (int i = 0; i < 32; i += 4) {
                float4 h0 = h4[i], h1 = h4[i + 1], h2 = h4[i + 2], h3 = h4[i + 3];
                a0 = fmaf(wr[i].w, h0.w, fmaf(wr[i].z, h0.z, fmaf(wr[i].y, h0.y, fmaf(wr[i].x, h0.x, a0))));
                a1 = fmaf(wr[i+1].w, h1.w, fmaf(wr[i+1].z, h1.z, fmaf(wr[i+1].y, h1.y, fmaf(wr[i+1].x, h1.x, a1))));
                a2 = fmaf(wr[i+2].w, h2.w, fmaf(wr[i+2].z, h2.z, fmaf(wr[i+2].y, h2.y, fmaf(wr[i+2].x, h2.x, a2))));
                a3 = fmaf(wr[i+3].w, h3.w, fmaf(wr[i+3].z, h3.z, fmaf(wr[i+3].y, h3.y, fmaf(wr[i+3].x, h3.x, a3))));
            }
            gi[(long)(m0 + s) * G3_ + g] = (a0 + a1) + (a2 + a3);
        }
    }
}

// ---------------------------------------------------------------------------
// K2/K4: GRU recurrence. One block per batch element, 384 threads.
// Thread g owns w_hh[g][0:128] in registers; h broadcast via LDS.
// gi layout [t*B+b][384]; y layout [t*B+b][128].
// ---------------------------------------------------------------------------
__global__ __launch_bounds__(384, 2) void gru_layer(
    const float* __restrict__ gi,    // [M,384]
    const float* __restrict__ w_hh,  // [384,128]
    const float* __restrict__ b_hh,  // [384]
    float* __restrict__ y)           // [M,128]
{
    const int g = threadIdx.x;
    const int b = blockIdx.x;

    float4 wr[32];
    const float4* w4 = (const float4*)(w_hh + g * 128);
#pragma unroll
    for (int i = 0; i < 32; i++) wr[i] = w4[i];
    const float bg = b_hh[g];

    __shared__ __align__(16) float h_lds[128];
    __shared__ float gh_lds[384];

    float h_own = 0.f;  // valid for g < 128
    if (g < 128) h_lds[g] = 0.f;
    __syncthreads();

    const float* gi_b = gi + (long)b * G3_;
    float* y_b = y + (long)b * H_;

    for (int t = 0; t < T_; t++) {
        const float* gi_t = gi_b + (long)t * (B_ * G3_);
        float ir = 0.f, iz = 0.f, in_ = 0.f;
        if (g < 128) {  // prefetch input gates (hidden behind the dot)
            ir = gi_t[g];
            iz = gi_t[128 + g];
            in_ = gi_t[256 + g];
        }
        // gh_g = b_hh[g] + dot(w_hh[g], h)
        const float4* h4 = (const float4*)h_lds;
        float a0 = bg, a1 = 0.f, a2 = 0.f, a3 = 0.f;
#pragma unroll
        for (int i = 0; i < 32; i += 4) {
            float4 h0 = h4[i], h1 = h4[i + 1], h2 = h4[i + 2], h3 = h4[i + 3];
            a0 = fmaf(wr[i].w, h0.w, fmaf(wr[i].z, h0.z, fmaf(wr[i].y, h0.y, fmaf(wr[i].x, h0.x, a0))));
            a1 = fmaf(wr[i+1].w, h1.w, fmaf(wr[i+1].z, h1.z, fmaf(wr[i+1].y, h1.y, fmaf(wr[i+1].x, h1.x, a1))));
            a2 = fmaf(wr[i+2].w, h2.w, fmaf(wr[i+2].z, h2.z, fmaf(wr[i+2].y, h2.y, fmaf(wr[i+2].x, h2.x, a2))));
            a3 = fmaf(wr[i+3].w, h3.w, fmaf(wr[i+3].z, h3.z, fmaf(wr[i+3].y, h3.y, fmaf(wr[i+3].x, h3.x, a3))));
        }
        gh_lds[g] = (a0 + a1) + (a2 + a3);
        __syncthreads();   // gh ready; h_lds reads done
        if (g < 128) {
            const float hr = gh_lds[g];
            const float hz = gh_lds[128 + g];
            const float hn = gh_lds[256 + g];
            const float r = 1.f / (1.f + __expf(-(ir + hr)));
            const float z = 1.f / (1.f + __expf(-(iz + hz)));
            const float narg = in_ + r * hn;
            // tanh(x) = 1 - 2/(exp(2x)+1)
            const float n = 1.f - 2.f / (__expf(2.f * narg) + 1.f);
            h_own = (1.f - z) * n + z * h_own;
            h_lds[g] = h_own;
            y_b[(long)t * (B_ * H_) + g] = h_own;
        }
        __syncthreads();   // h_lds updated for next step
    }
}

// ---------------------------------------------------------------------------
// K5: out[b*T+t][c] = relu(fc_b[c] + dot(fc_w[c], y[t*B+b]))
// 256 threads: thread = slot(0..7) * 32 + c ; 8 tokens per pass.
// ---------------------------------------------------------------------------
__global__ __launch_bounds__(256, 2) void fc_relu(
    const float* __restrict__ y,     // [M,128]
    const float* __restrict__ fc_w,  // [32,128]
    const float* __restrict__ fc_b,  // [32]
    float* __restrict__ out)         // [B*T,32]
{
    const int tid = threadIdx.x;
    const int c = tid & 31;
    const int slot = tid >> 5;

    float4 wr[32];
    const float4* w4 = (const float4*)(fc_w + c * 128);
#pragma unroll
    for (int i = 0; i < 32; i++) wr[i] = w4[i];
    const float bc = fc_b[c];

    __shared__ __align__(16) float rows[8][128];

    for (int grp = blockIdx.x; grp < M_ / 8; grp += gridDim.x) {
        const int m0 = grp * 8;
        __syncthreads();
        for (int i = tid; i < 8 * 128; i += 256) {
            rows[i >> 7][i & 127] = y[(long)m0 * 128 + i];
        }
        __syncthreads();
        const float4* h4 = (const float4*)rows[slot];
        float a0 = bc, a1 = 0.f, a2 = 0.f, a3 = 0.f;
#pragma unroll
        for (int i = 0; i < 32; i += 4) {
            float4 h0 = h4[i], h1 = h4[i + 1], h2 = h4[i + 2], h3 = h4[i + 3];
            a0 = fmaf(wr[i].w, h0.w, fmaf(wr[i].z, h0.z, fmaf(wr[i].y, h0.y, fmaf(wr[i].x, h0.x, a0))));
            a1 = fmaf(wr[i+1].w, h1.w, fmaf(wr[i+1].z, h1.z, fmaf(wr[i+1].y, h1.y, fmaf(wr[i+1].x, h1.x, a1))));
            a2 = fmaf(wr[i+2].w, h2.w, fmaf(wr[i+2].z, h2.z, fmaf(wr[i+2].y, h2.y, fmaf(wr[i+2].x, h2.x, a2))));
            a3 = fmaf(wr[i+3].w, h3.w, fmaf(wr[i+3].z, h3.z, fmaf(wr[i+3].y, h3.y, fmaf(wr[i+3].x, h3.x, a3))));
        }
        float acc = (a0 + a1) + (a2 + a3);
        acc = fmaxf(acc, 0.f);
        const int m = m0 + slot;
        const int t = m >> 6;
        const int b = m & 63;
        out[((long)b * T_ + t) * C_ + c] = acc;
    }
}

// ---------------------------------------------------------------------------
extern "C" void kernel_launch(void* const* d_in, const int* in_sizes, int n_in,
                              void* d_out, int out_size, void* d_ws, size_t ws_size,
                              hipStream_t stream) {
    const int*   x     = (const int*)d_in[0];
    const float* emb   = (const float*)d_in[1];
    const float* w_ih0 = (const float*)d_in[2];
    const float* w_hh0 = (const float*)d_in[3];
    const float* b_ih0 = (const float*)d_in[4];
    const float* b_hh0 = (const float*)d_in[5];
    const float* w_ih1 = (const float*)d_in[6];
    const float* w_hh1 = (const float*)d_in[7];
    const float* b_ih1 = (const float*)d_in[8];
    const float* b_hh1 = (const float*)d_in[9];
    const float* fc_w  = (const float*)d_in[10];
    const float* fc_b  = (const float*)d_in[11];
    float* out = (float*)d_out;

    // workspace: gi [M,384] fp32 (201.3 MB, reused for both layers) + y [M,128] (67.1 MB)
    float* gi = (float*)d_ws;
    float* yb = (float*)((char*)d_ws + (size_t)M_ * G3_ * sizeof(float));

    // layer 0 input gates (embedding gather fused)
    gates_gemm<true><<<512, 384, 0, stream>>>(emb, x, w_ih0, b_ih0, gi);
    // layer 0 recurrence
    gru_layer<<<B_, 384, 0, stream>>>(gi, w_hh0, b_hh0, yb);
    // layer 1 input gates
    gates_gemm<false><<<512, 384, 0, stream>>>(yb, nullptr, w_ih1, b_ih1, gi);
    // layer 1 recurrence (overwrites yb; gi1 already computed)
    gru_layer<<<B_, 384, 0, stream>>>(gi, w_hh1, b_hh1, yb);
    // FC + ReLU
    fc_relu<<<512, 256, 0, stream>>>(yb, fc_w, fc_b, out);
}